// Round 7
// baseline (131.279 us; speedup 1.0000x reference)
//
#include <hip/hip_runtime.h>
#include <hip/hip_bf16.h>

typedef __attribute__((ext_vector_type(4))) float f32x4;
typedef __attribute__((ext_vector_type(8))) short bf16x8;
typedef __attribute__((ext_vector_type(4))) short short4v;

#define ACH 1032       // shorts per Ab row (1024 + 8 pad); 2064B stride -> 2-way max on b128 frag reads
#define AB_BYTES 66048 // 32 * 2064
#define CS 516         // dwords per epilogue c row (512 + 4 pad)

__device__ __forceinline__ short f2bf(float f) {
  __hip_bfloat16 h = __float2bfloat16(f);
  return __builtin_bit_cast(short, h);
}

// global_load_lds width 16: wave-uniform LDS base + lane*16, per-lane gsrc.
#define GLD_LDS16(gp, lp)                                                    \
  __builtin_amdgcn_global_load_lds(                                          \
      (const __attribute__((address_space(1))) unsigned int*)(gp),           \
      (__attribute__((address_space(3))) unsigned int*)(lp), 16, 0, 0)

#define WAITV(N)                                            \
  {                                                         \
    asm volatile("s_waitcnt vmcnt(" #N ")" ::: "memory");   \
    __builtin_amdgcn_sched_barrier(0);                      \
  }
// lgkm-only barrier: LDS ops complete; vmcnt pipelines legally cross it.
#define QBAR()                                              \
  {                                                         \
    asm volatile("s_waitcnt lgkmcnt(0)" ::: "memory");      \
    __builtin_amdgcn_sched_barrier(0);                      \
    __builtin_amdgcn_s_barrier();                           \
    __builtin_amdgcn_sched_barrier(0);                      \
  }

// ---------------------------------------------------------------------------
// GEMM view: C[8192 x 512] = A[8192 x 1024] * B[1024 x 512], k = j*4 + kc,
// kc -> x component {0,1,2,4}.  512 cols = [c0 of i=0..255 | c4 of i=0..255].
// Bp (ws, 1 MB): per-lane MFMA B-fragment order Bp[it][cg][lane][8 shorts].
// ---------------------------------------------------------------------------
__global__ __launch_bounds__(256) void ga_prep_B(const float* __restrict__ W,
                                                 short* __restrict__ Bp) {
  const int gid = blockIdx.x * 256 + threadIdx.x;  // 65536 = 32 it * 32 cg * 64 lane
  const int l  = gid & 63;
  const int cg = (gid >> 6) & 31;
  const int it = gid >> 11;
  const int ln = l & 15, q = l >> 4;
  const int hc = cg >> 4;                 // 0 -> c0 row, 1 -> c4 row
  const int i  = (cg & 15) * 16 + ln;
  const int j0 = it * 8 + q * 2;
  const float4* W4 = (const float4*)W;

  bf16x8 o;
#pragma unroll
  for (int jj = 0; jj < 2; ++jj) {
    const float4 wv = W4[((j0 + jj) * 256 + i) * 2];  // W[j][i][0..3]
    if (!hc) {
      o[jj * 4 + 0] = f2bf(wv.x); o[jj * 4 + 1] = f2bf(wv.y);
      o[jj * 4 + 2] = f2bf(wv.z); o[jj * 4 + 3] = 0;
    } else {
      o[jj * 4 + 0] = 0;           o[jj * 4 + 1] = f2bf(wv.z);
      o[jj * 4 + 2] = f2bf(-wv.y); o[jj * 4 + 3] = f2bf(wv.x);
    }
  }
  *(bf16x8*)&Bp[(size_t)gid * 8] = o;
}

// ---------------------------------------------------------------------------
// Main: 256 blocks (32 rows x ALL 512 cols) x 1024 threads (16 waves).
// K (1024) split into 8 batches of 32 j (128 k). Pipeline per batch g:
//   CONV(g): x regs (loaded 2 batches ahead) -> bf16 -> Ab[:, slice g]; QBAR
//   4 MFMA iters on slice g: af from Ab; B frags from a 2-slice LDS ring
//     filled by per-wave global_load_lds DMA (wave w DMAs exactly the 2KB
//     it reads -> NO cross-wave dep -> no barriers in the MFMA loop; own
//     counted vmcnt(2) per iter: slice it always has >=2 newer DMA ops).
//   x batch g+2 issued mid-batch: x-HBM latency hides under B-L2 + MFMA.
// Three memory streams (x read / B L2 / y write via tail) overlap instead
// of running as serial phases. 8 QBARs total, zero vmcnt(0) until the end.
// Epilogue: two 16-row passes via c_lds (aliases B ring), nontemporal writes.
// ---------------------------------------------------------------------------
__global__ __launch_bounds__(1024, 4) void ga_mv_main(
    const float* __restrict__ x, const short* __restrict__ Bp,
    const float* __restrict__ bias, float* __restrict__ y) {
  __shared__ __align__(16) char smem[131584];  // 66048 Ab + 2*32768 B ring
  short* Ab = (short*)smem;
  short* Bs = (short*)(smem + AB_BYTES);       // B slice ring
  float* c_lds = (float*)(smem + AB_BYTES);    // epilogue alias (B dead)

  const int t = threadIdx.x;
  const int lane = t & 63, w = t >> 6;
  const int ln = lane & 15, qq = lane >> 4;
  const int R0 = blockIdx.x * 32;

  // ---- x staging (registers): thread t owns (row = t>>5, j-col = t&31) of
  // each batch; batch g at j = 32g + (t&31). 32B/thread/batch, coalesced
  // (32 lanes span 1KB contiguous).
  const float* xsrc = x + (size_t)(R0 + (t >> 5)) * 2048 + (t & 31) * 8;
  const int crow = t >> 5, cj = t & 31;
  f32x4 xA0, xA1, xB0, xB1;

#define XLOAD(g)                                                \
  {                                                             \
    const f32x4* p = (const f32x4*)(xsrc + (g) * 256);          \
    if ((g) & 1) { xB0 = p[0]; xB1 = p[1]; }                    \
    else         { xA0 = p[0]; xA1 = p[1]; }                    \
  }

#define CONV(g)                                                 \
  {                                                             \
    const f32x4 v0 = ((g) & 1) ? xB0 : xA0;                     \
    const f32x4 v1 = ((g) & 1) ? xB1 : xA1;                     \
    short4v a;                                                  \
    a[0] = f2bf(v0[0]); a[1] = f2bf(v0[1]);                     \
    a[2] = f2bf(v0[2]); a[3] = f2bf(v1[0]);                     \
    *(short4v*)&Ab[crow * ACH + (32 * (g) + cj) * 4] = a;       \
  }

  // ---- B slice DMA: slice s (32KB = k-block of iter s) -> ring buf s&1.
  // Wave w stages ONLY its own 2KB read region.
  const int boff = w * 1024 + lane * 8;  // shorts
#define BDMA(s)                                                 \
  {                                                             \
    const short* gp = Bp + (size_t)(s) * 16384 + boff;          \
    short* lp = Bs + ((s) & 1) * 16384 + boff;                  \
    GLD_LDS16(gp, lp);                                          \
    GLD_LDS16(gp + 512, lp + 512);                              \
  }

  f32x4 acc[2][2] = {};

#define ITER(it, N)                                                           \
  {                                                                           \
    WAITV(N); /* own DMA for slice it retired */                              \
    const bf16x8 af0 = *(const bf16x8*)&Ab[ln * ACH + (it) * 32 + qq * 8];    \
    const bf16x8 af1 =                                                        \
        *(const bf16x8*)&Ab[(16 + ln) * ACH + (it) * 32 + qq * 8];            \
    const bf16x8 bf0 = *(const bf16x8*)&Bs[((it) & 1) * 16384 + boff];        \
    const bf16x8 bf1 = *(const bf16x8*)&Bs[((it) & 1) * 16384 + boff + 512];  \
    acc[0][0] = __builtin_amdgcn_mfma_f32_16x16x32_bf16(af0, bf0, acc[0][0],  \
                                                        0, 0, 0);             \
    acc[1][0] = __builtin_amdgcn_mfma_f32_16x16x32_bf16(af1, bf0, acc[1][0],  \
                                                        0, 0, 0);             \
    acc[0][1] = __builtin_amdgcn_mfma_f32_16x16x32_bf16(af0, bf1, acc[0][1],  \
                                                        0, 0, 0);             \
    acc[1][1] = __builtin_amdgcn_mfma_f32_16x16x32_bf16(af1, bf1, acc[1][1],  \
                                                        0, 0, 0);             \
    __builtin_amdgcn_sched_barrier(0); /* WAR: DMA below after reads above */ \
    if ((it) + 2 < 32) BDMA((it) + 2);                                        \
  }

  // batch: convert slice g (compiler inserts exact vmcnt for x-reg use),
  // publish, run its 4 iters; issue x(g+2) mid-batch.
#define BATCH(g, DOX, NT3)         \
  {                                \
    CONV(g);                       \
    QBAR();                        \
    ITER(4 * (g) + 0, 2)           \
    ITER(4 * (g) + 1, 2)           \
    if (DOX) XLOAD((g) + 2);       \
    ITER(4 * (g) + 2, 2)           \
    ITER(4 * (g) + 3, NT3)         \
  }

  // ---- prologue ----
  BDMA(0);
  BDMA(1);
  XLOAD(0);
  XLOAD(1);

  BATCH(0, 1, 2) BATCH(1, 1, 2) BATCH(2, 1, 2) BATCH(3, 1, 2)
  BATCH(4, 1, 2) BATCH(5, 1, 2) BATCH(6, 0, 2) BATCH(7, 0, 0)

  QBAR();  // all waves done with Ab/B ring before c_lds alias writes

  // ---- epilogue: two 16-row passes; acc[ep] -> c_lds -> full-mv y writes.
  // C/D layout: col = ln, row(within 16-tile) = qq*4 + r.
  const int h = t & 1, p = (t >> 1) & 255, rh = t >> 9;
  const float4 bv = ((const float4*)bias)[p * 2 + h];
  f32x4* y4 = (f32x4*)y;

#pragma unroll
  for (int ep = 0; ep < 2; ++ep) {
    if (ep) QBAR();  // pass-0 c_lds reads done before pass-1 writes
#pragma unroll
    for (int n = 0; n < 2; ++n)
#pragma unroll
      for (int r = 0; r < 4; ++r)
        c_lds[(qq * 4 + r) * CS + w * 32 + n * 16 + ln] = acc[ep][n][r];
    QBAR();  // all waves' c_lds writes visible
#pragma unroll
    for (int rr = 0; rr < 8; ++rr) {
      const int row = rr * 2 + rh;
      f32x4 o;
      o[0] = bv.x; o[1] = bv.y; o[2] = bv.z; o[3] = bv.w;
      o[0] += c_lds[row * CS + h * 256 + p];  // +c0 into comp0 / +c4 into comp4
      __builtin_nontemporal_store(
          o, &y4[((size_t)(R0 + ep * 16 + row) * 256 + p) * 2 + h]);
    }
  }
}

extern "C" void kernel_launch(void* const* d_in, const int* in_sizes, int n_in,
                              void* d_out, int out_size, void* d_ws, size_t ws_size,
                              hipStream_t stream) {
  const float* x = (const float*)d_in[0];
  const float* W = (const float*)d_in[1];
  const float* bias = (const float*)d_in[2];
  float* y = (float*)d_out;
  short* Bp = (short*)d_ws;  // 1 MB

  ga_prep_B<<<dim3(256), dim3(256), 0, stream>>>(W, Bp);
  ga_mv_main<<<dim3(256), dim3(1024), 0, stream>>>(x, Bp, bias, y);
}

// Round 8
// 125.916 us; speedup vs baseline: 1.0426x; 1.0426x over previous
//
#include <hip/hip_runtime.h>
#include <hip/hip_bf16.h>

typedef __attribute__((ext_vector_type(4))) float f32x4;
typedef __attribute__((ext_vector_type(4))) unsigned int u32x4;
typedef __attribute__((ext_vector_type(8))) short bf16x8;
typedef __attribute__((ext_vector_type(4))) short short4v;

#define ACH 1032       // shorts per Ab row (1024 + 8 pad); 2064B stride -> 2-way max on b128 frag reads
#define AB_BYTES 66048 // 32 * 2064
#define CS 516         // dwords per epilogue c row (512 + 4 pad)

__device__ __forceinline__ short f2bf(float f) {
  __hip_bfloat16 h = __float2bfloat16(f);
  return __builtin_bit_cast(short, h);
}

// lgkm-only barrier: LDS ops complete; vmcnt pipelines legally cross it.
#define QBAR()                                              \
  {                                                         \
    asm volatile("s_waitcnt lgkmcnt(0)" ::: "memory");      \
    __builtin_amdgcn_sched_barrier(0);                      \
    __builtin_amdgcn_s_barrier();                           \
    __builtin_amdgcn_sched_barrier(0);                      \
  }

// ---------------------------------------------------------------------------
// GEMM view: C[8192 x 512] = A[8192 x 1024] * B[1024 x 512], k = j*4 + kc,
// kc -> x component {0,1,2,4}.  512 cols = [c0 of i=0..255 | c4 of i=0..255].
// KEY REDUNDANCY: the c4-half of B is a permutation/negation of the c0-half
//   (c0 frag per j: [w0,w1,w2,0]; c4 frag: [0,w2,-w1,w0]).  Bp therefore
// stores ONLY the c0 half: Bp[it=0..31][cg=0..15][lane][8 shorts] = 512 KB.
// Main builds the c4 fragment in-register (6 VALU ops) -> aggregate B-cache
// traffic halves (256->128 MB) and each loaded B byte feeds 2x the MFMAs.
// ---------------------------------------------------------------------------
__global__ __launch_bounds__(256) void ga_prep_B(const float* __restrict__ W,
                                                 short* __restrict__ Bp) {
  const int gid = blockIdx.x * 256 + threadIdx.x;  // 32768 = 32 it * 16 cg * 64 lane
  const int l  = gid & 63;
  const int cg = (gid >> 6) & 15;
  const int it = gid >> 10;
  const int ln = l & 15, q = l >> 4;
  const int i  = cg * 16 + ln;
  const int j0 = it * 8 + q * 2;
  const float4* W4 = (const float4*)W;

  bf16x8 o;
#pragma unroll
  for (int jj = 0; jj < 2; ++jj) {
    const float4 wv = W4[((j0 + jj) * 256 + i) * 2];  // W[j][i][0..3]
    o[jj * 4 + 0] = f2bf(wv.x); o[jj * 4 + 1] = f2bf(wv.y);
    o[jj * 4 + 2] = f2bf(wv.z); o[jj * 4 + 3] = 0;
  }
  *(bf16x8*)&Bp[(size_t)gid * 8] = o;
}

// ---------------------------------------------------------------------------
// Main: 256 blocks (32 rows x ALL 512 cols) x 1024 threads (16 waves).
// Wave w owns col-group w: c0 cols 16w..16w+15 AND c4 cols 256+16w..+15.
// K in 8 batches of 32 j: CONV (x regs, loaded 2 batches ahead -> bf16 ->
// Ab slice), QBAR, then 4 iters x {2 ds_read_b128 A + 1 KB B frag (reg
// pipeline depth 4, compiler-managed waits) + build c4 frag in-register +
// 4 MFMA}.  8 QBARs total, no vmcnt drains until the end.
// Epilogue: two 16-row passes via c_lds (aliases Ab), nontemporal writes.
// ---------------------------------------------------------------------------
__global__ __launch_bounds__(1024, 4) void ga_mv_main(
    const float* __restrict__ x, const short* __restrict__ Bp,
    const float* __restrict__ bias, float* __restrict__ y) {
  __shared__ __align__(16) char smem[AB_BYTES];
  short* Ab = (short*)smem;
  float* c_lds = (float*)smem;  // epilogue alias (Ab dead by then): 33024 B

  const int t = threadIdx.x;
  const int lane = t & 63, w = t >> 6;
  const int ln = lane & 15, qq = lane >> 4;
  const int R0 = blockIdx.x * 32;

  // ---- x staging (registers): thread t owns (row = t>>5, j-col = t&31) of
  // each batch; batch g at j = 32g + (t&31). 32B/thread/batch, coalesced.
  const float* xsrc = x + (size_t)(R0 + (t >> 5)) * 2048 + (t & 31) * 8;
  const int crow = t >> 5, cj = t & 31;
  f32x4 xA0, xA1, xB0, xB1;

#define XLOAD(g)                                                \
  {                                                             \
    const f32x4* p = (const f32x4*)(xsrc + (g) * 256);          \
    if ((g) & 1) { xB0 = p[0]; xB1 = p[1]; }                    \
    else         { xA0 = p[0]; xA1 = p[1]; }                    \
  }

#define CONV(g)                                                 \
  {                                                             \
    const f32x4 v0 = ((g) & 1) ? xB0 : xA0;                     \
    const f32x4 v1 = ((g) & 1) ? xB1 : xA1;                     \
    short4v a;                                                  \
    a[0] = f2bf(v0[0]); a[1] = f2bf(v0[1]);                     \
    a[2] = f2bf(v0[2]); a[3] = f2bf(v1[0]);                     \
    *(short4v*)&Ab[crow * ACH + (32 * (g) + cj) * 4] = a;       \
  }

  // ---- B frag pipeline (registers, depth 4). Wave w reads ONLY cg w:
  // 1 KB per slice, 32 KB total per wave (was 64 KB).
  const size_t bbase = (size_t)w * 512 + lane * 8;
  bf16x8 Bf[4];
#define LB(itv, b) { Bf[b] = *(const bf16x8*)(Bp + (size_t)(itv) * 8192 + bbase); }

  f32x4 acc[2][2] = {};

#define ITER(it)                                                              \
  {                                                                           \
    const bf16x8 af0 = *(const bf16x8*)&Ab[ln * ACH + (it) * 32 + qq * 8];    \
    const bf16x8 af1 =                                                        \
        *(const bf16x8*)&Ab[(16 + ln) * ACH + (it) * 32 + qq * 8];            \
    const bf16x8 F = Bf[(it) & 3];                                            \
    const u32x4 fu = __builtin_bit_cast(u32x4, F);                            \
    u32x4 gu;                                                                 \
    gu.x = fu.y << 16;                               /* [0, w2]        */     \
    gu.y = ((fu.x >> 16) | (fu.x << 16)) ^ 0x8000u;  /* [-w1, w0]      */     \
    gu.z = fu.w << 16;                                                        \
    gu.w = ((fu.z >> 16) | (fu.z << 16)) ^ 0x8000u;                           \
    const bf16x8 G = __builtin_bit_cast(bf16x8, gu);                          \
    acc[0][0] = __builtin_amdgcn_mfma_f32_16x16x32_bf16(af0, F, acc[0][0],    \
                                                        0, 0, 0);             \
    acc[1][0] = __builtin_amdgcn_mfma_f32_16x16x32_bf16(af1, F, acc[1][0],    \
                                                        0, 0, 0);             \
    acc[0][1] = __builtin_amdgcn_mfma_f32_16x16x32_bf16(af0, G, acc[0][1],    \
                                                        0, 0, 0);             \
    acc[1][1] = __builtin_amdgcn_mfma_f32_16x16x32_bf16(af1, G, acc[1][1],    \
                                                        0, 0, 0);             \
    if ((it) + 4 < 32) LB((it) + 4, (it) & 3);                                \
  }

#define BATCH(g, DOX)              \
  {                                \
    CONV(g);                       \
    QBAR();                        \
    ITER(4 * (g) + 0)              \
    ITER(4 * (g) + 1)              \
    if (DOX) XLOAD((g) + 2);       \
    ITER(4 * (g) + 2)              \
    ITER(4 * (g) + 3)              \
  }

  // ---- prologue ----
  LB(0, 0); LB(1, 1); LB(2, 2); LB(3, 3);
  XLOAD(0);
  XLOAD(1);

  BATCH(0, 1) BATCH(1, 1) BATCH(2, 1) BATCH(3, 1)
  BATCH(4, 1) BATCH(5, 1) BATCH(6, 0) BATCH(7, 0)

  QBAR();  // all waves done with Ab before c_lds alias writes

  // ---- epilogue: two 16-row passes; acc[ep] -> c_lds -> full-mv y writes.
  // C/D layout: col = ln, row(within 16-tile) = qq*4 + r.
  // Wave w's cols: n=0 -> 16w (c0), n=1 -> 256+16w (c4).
  const int h = t & 1, p = (t >> 1) & 255, rh = t >> 9;
  const float4 bv = ((const float4*)bias)[p * 2 + h];
  f32x4* y4 = (f32x4*)y;

#pragma unroll
  for (int ep = 0; ep < 2; ++ep) {
    if (ep) QBAR();  // pass-0 c_lds reads done before pass-1 writes
#pragma unroll
    for (int n = 0; n < 2; ++n)
#pragma unroll
      for (int r = 0; r < 4; ++r)
        c_lds[(qq * 4 + r) * CS + n * 256 + w * 16 + ln] = acc[ep][n][r];
    QBAR();  // all waves' c_lds writes visible
#pragma unroll
    for (int rr = 0; rr < 8; ++rr) {
      const int row = rr * 2 + rh;
      f32x4 o;
      o[0] = bv.x; o[1] = bv.y; o[2] = bv.z; o[3] = bv.w;
      o[0] += c_lds[row * CS + h * 256 + p];  // +c0 into comp0 / +c4 into comp4
      __builtin_nontemporal_store(
          o, &y4[((size_t)(R0 + ep * 16 + row) * 256 + p) * 2 + h]);
    }
  }
}

extern "C" void kernel_launch(void* const* d_in, const int* in_sizes, int n_in,
                              void* d_out, int out_size, void* d_ws, size_t ws_size,
                              hipStream_t stream) {
  const float* x = (const float*)d_in[0];
  const float* W = (const float*)d_in[1];
  const float* bias = (const float*)d_in[2];
  float* y = (float*)d_out;
  short* Bp = (short*)d_ws;  // 512 KB (c0 half only)

  ga_prep_B<<<dim3(128), dim3(256), 0, stream>>>(W, Bp);
  ga_mv_main<<<dim3(256), dim3(1024), 0, stream>>>(x, Bp, bias, y);
}